// Round 8
// baseline (32.312 us; speedup 1.0000x reference)
//
#include <hip/hip_runtime.h>
#include <cstdint>

#define IN_F 128
#define OUT_F 128
#define NPB 4       // nodes per block
#define WAVES 8
#define THREADS 512
#define STRIP 128   // j-columns per wave (N / WAVES)
#define NEG_BIG -1e30f

__global__ __launch_bounds__(THREADS, 4) void sage_kernel(
    const float* __restrict__ h, const int* __restrict__ adj,
    const float* __restrict__ Ws, const float* __restrict__ bs,
    const float* __restrict__ Wn, const float* __restrict__ bn,
    const float* __restrict__ gamma, const float* __restrict__ beta,
    float* __restrict__ out, int N)
{
    // 16 KB buffer, time-shared: scan partials (f32x2) -> GEMM partials
    __shared__ __align__(16) char spraw[WAVES * NPB * 64 * 8];
    auto scanp = (float2 (*)[NPB][64])spraw;        // [WAVES][NPB][64]
    auto gemmp = (float (*)[NPB][OUT_F])spraw;      // [NPB][NPB][OUT_F] (8 KB)

    __shared__ unsigned anyw_s[WAVES];
    __shared__ float h_self[NPB][IN_F];             // 2 KB
    __shared__ float agg_s[NPB][IN_F];              // 2 KB

    const int t    = threadIdx.x;
    const int w    = t >> 6;
    const int lane = t & 63;

    const int base = blockIdx.x * NPB;
    const int b    = base / N;
    const int i0   = base - b * N;

    const float* hb   = h   + (size_t)b * N * IN_F;
    const int*   adjb = adj + (size_t)b * N * N;
    const int jbase   = w * STRIP;

    // ---- masks: two 64-bit words per node over this wave's 128-col strip ----
    unsigned long long mlo[NPB], mhi[NPB];
    unsigned anybits = 0;
    #pragma unroll
    for (int n = 0; n < NPB; ++n) {
        const int i_n = i0 + n;
        const int j1  = jbase + lane;
        const int j2  = jbase + 64 + lane;
        mlo[n] = __ballot(adjb[(size_t)i_n * N + j1] != 0 && j1 != i_n);
        mhi[n] = __ballot(adjb[(size_t)i_n * N + j2] != 0 && j2 != i_n);
        anybits |= ((mlo[n] | mhi[n]) != 0ull ? 1u : 0u) << n;
    }

    // ---- dense masked-max scan (f32): pairs of j's, min/min/max3 ----
    float ax[NPB], ay[NPB];
    #pragma unroll
    for (int n = 0; n < NPB; ++n) { ax[n] = NEG_BIG; ay[n] = NEG_BIG; }

    const float* hrow = hb + (size_t)jbase * IN_F + 2 * lane;
    const float PINF = __builtin_inff();

    #pragma unroll 4
    for (int kk = 0; kk < 32; ++kk) {
        const float2 v0 = *(const float2*)(hrow + (size_t)(2 * kk)     * IN_F);
        const float2 v1 = *(const float2*)(hrow + (size_t)(2 * kk + 1) * IN_F);
        #pragma unroll
        for (int n = 0; n < NPB; ++n) {
            const float c0 = ((mlo[n] >> (2 * kk))     & 1ull) ? PINF : -PINF; // s_cselect
            const float c1 = ((mlo[n] >> (2 * kk + 1)) & 1ull) ? PINF : -PINF;
            ax[n] = fmaxf(fmaxf(fminf(v0.x, c0), fminf(v1.x, c1)), ax[n]);     // v_max3
            ay[n] = fmaxf(fmaxf(fminf(v0.y, c0), fminf(v1.y, c1)), ay[n]);
        }
    }
    #pragma unroll 4
    for (int kk = 0; kk < 32; ++kk) {
        const float2 v0 = *(const float2*)(hrow + (size_t)(64 + 2 * kk)     * IN_F);
        const float2 v1 = *(const float2*)(hrow + (size_t)(64 + 2 * kk + 1) * IN_F);
        #pragma unroll
        for (int n = 0; n < NPB; ++n) {
            const float c0 = ((mhi[n] >> (2 * kk))     & 1ull) ? PINF : -PINF;
            const float c1 = ((mhi[n] >> (2 * kk + 1)) & 1ull) ? PINF : -PINF;
            ax[n] = fmaxf(fmaxf(fminf(v0.x, c0), fminf(v1.x, c1)), ax[n]);
            ay[n] = fmaxf(fmaxf(fminf(v0.y, c0), fminf(v1.y, c1)), ay[n]);
        }
    }

    #pragma unroll
    for (int n = 0; n < NPB; ++n) scanp[w][n][lane] = make_float2(ax[n], ay[n]);
    if (lane == 0) anyw_s[w] = anybits;
    __syncthreads();

    // ---- combine partials (waves 0-3) / stage h_self (waves 4-7) ----
    if (w < NPB) {
        float rx = NEG_BIG, ry = NEG_BIG;
        #pragma unroll
        for (int wp = 0; wp < WAVES; ++wp) {
            const float2 p = scanp[wp][w][lane];
            rx = fmaxf(rx, p.x);
            ry = fmaxf(ry, p.y);
        }
        unsigned anyall = 0;
        #pragma unroll
        for (int wp = 0; wp < WAVES; ++wp) anyall |= anyw_s[wp];
        const float2 hs = *(const float2*)&hb[(size_t)(i0 + w) * IN_F + 2 * lane];
        if (!((anyall >> w) & 1u)) { rx = hs.x; ry = hs.y; }
        *(float2*)&agg_s[w][2 * lane] = make_float2(rx, ry);
    } else {
        const int n2 = w - NPB;
        const float2 hs = *(const float2*)&hb[(size_t)(i0 + n2) * IN_F + 2 * lane];
        *(float2*)&h_self[n2][2 * lane] = hs;
    }
    __syncthreads();   // scanp fully consumed; gemmp may now overwrite it

    // ---- GEMMs: thread (o = t&127, fchunk = t>>7) handles ALL 4 nodes ----
    {
        const int o  = t & (OUT_F - 1);
        const int fc = t >> 7;               // 0..3, wave-uniform (w>>1)
        float acc[NPB];
        #pragma unroll
        for (int n = 0; n < NPB; ++n) acc[n] = 0.0f;

        const int f0 = fc * (IN_F / NPB);    // 32 f's per chunk
        #pragma unroll 8
        for (int ff = 0; ff < IN_F / NPB; ++ff) {
            const int f = f0 + ff;
            const float ws = Ws[f * OUT_F + o];
            const float wn = Wn[f * OUT_F + o];
            #pragma unroll
            for (int n = 0; n < NPB; ++n) {
                acc[n] = fmaf(h_self[n][f], ws, acc[n]);  // uniform LDS broadcast
                acc[n] = fmaf(agg_s[n][f],  wn, acc[n]);
            }
        }
        #pragma unroll
        for (int n = 0; n < NPB; ++n) gemmp[fc][n][o] = acc[n];
    }
    __syncthreads();

    // ---- merged reduce + bias + LayerNorm + ReLU (waves 0-3, node w) ----
    if (w < NPB) {
        float x0 = bs[lane]      + bn[lane];
        float x1 = bs[lane + 64] + bn[lane + 64];
        #pragma unroll
        for (int fc = 0; fc < NPB; ++fc) {
            x0 += gemmp[fc][w][lane];
            x1 += gemmp[fc][w][lane + 64];
        }
        float s  = x0 + x1;
        float s2 = x0 * x0 + x1 * x1;
        #pragma unroll
        for (int d = 32; d >= 1; d >>= 1) {
            s  += __shfl_xor(s, d, 64);
            s2 += __shfl_xor(s2, d, 64);
        }
        const float mu  = s * (1.0f / OUT_F);
        const float var = s2 * (1.0f / OUT_F) - mu * mu;
        const float rs  = rsqrtf(var + 1e-5f);

        float* orow = out + (size_t)(base + w) * OUT_F;
        const float r0 = (x0 - mu) * rs * gamma[lane]      + beta[lane];
        const float r1 = (x1 - mu) * rs * gamma[lane + 64] + beta[lane + 64];
        orow[lane]      = fmaxf(r0, 0.0f);
        orow[lane + 64] = fmaxf(r1, 0.0f);
    }
}

extern "C" void kernel_launch(void* const* d_in, const int* in_sizes, int n_in,
                              void* d_out, int out_size, void* d_ws, size_t ws_size,
                              hipStream_t stream) {
    const float* h     = (const float*)d_in[0];
    const int*   adj   = (const int*)d_in[1];
    const float* Ws    = (const float*)d_in[2];
    const float* bs    = (const float*)d_in[3];
    const float* Wn    = (const float*)d_in[4];
    const float* bn    = (const float*)d_in[5];
    const float* gamma = (const float*)d_in[6];
    const float* beta  = (const float*)d_in[7];
    float* out = (float*)d_out;

    const long long bn_nodes = in_sizes[0] / IN_F;          // B*N
    const int N = (int)((long long)in_sizes[1] / bn_nodes); // adj is B*N*N
    const int grid = (int)(bn_nodes / NPB);

    hipLaunchKernelGGL(sage_kernel, dim3(grid), dim3(THREADS), 0, stream,
                       h, adj, Ws, bs, Wn, bn, gamma, beta, out, N);
}